// Round 9
// baseline (1299.530 us; speedup 1.0000x reference)
//
#include <hip/hip_runtime.h>
#include <math.h>

#define TS 512
#define NB 64
#define NF 64
#define NE 256
#define NH 512
#define NO 128

#define NGRP 4     // batch groups (16 rows each)
#define NSLC 32    // h-slices per group (16 h-idx each)  [R15 structure]
#define RPG  16    // rows per group (dense MFMA A)

// ws layout (float words)
#define OFF_WCOMB 0        // 2048*64
#define OFF_BCOMB 131072   // 2048
#define OFF_HBUF  133120   // u32[2][4][512h][16b] tagged h words = 65536
#define OFF_POOL  198656   // 64*512

typedef short bf16x8 __attribute__((ext_vector_type(8)));
typedef float f32x4 __attribute__((ext_vector_type(4)));
typedef unsigned long long u64;
typedef unsigned int u32;

union F8 { bf16x8 s; unsigned short u[8]; };

__device__ __forceinline__ unsigned short f2bf(float f) {
    unsigned u = __float_as_uint(f);
    u += 0x7fffu + ((u >> 16) & 1u);
    return (unsigned short)(u >> 16);
}
__device__ __forceinline__ float bf2f(unsigned short h) {
    return __uint_as_float(((unsigned)h) << 16);
}
__device__ __forceinline__ float fast_sigmoid(float v) {
    return 1.f / (1.f + __expf(-v));
}
__device__ __forceinline__ float fast_tanh(float v) {
    return 1.f - 2.f / (1.f + __expf(2.f * v));
}
__device__ __forceinline__ u32 aload(const u32* p) {
    return __hip_atomic_load(p, __ATOMIC_RELAXED, __HIP_MEMORY_SCOPE_AGENT);
}

// W_comb[g][f] = sum_e W_ih[g][e] * W_emb[e][f];  b_comb[g] = W_ih[g]·b_emb + b_ih[g] + b_hh[g]
__global__ __launch_bounds__(256) void k_wcomb(const float* __restrict__ W_emb,
                                               const float* __restrict__ b_emb,
                                               const float* __restrict__ W_ih,
                                               const float* __restrict__ b_ih,
                                               const float* __restrict__ b_hh,
                                               float* __restrict__ W_comb,
                                               float* __restrict__ b_comb) {
    __shared__ float wih[4][NE];
    int g0 = blockIdx.x * 4;
    for (int i = threadIdx.x; i < 4 * NE; i += 256)
        wih[i >> 8][i & 255] = W_ih[(size_t)g0 * NE + i];
    __syncthreads();
    int gl = threadIdx.x >> 6, f = threadIdx.x & 63;
    float acc = 0.f;
    for (int e = 0; e < NE; ++e) acc += wih[gl][e] * W_emb[e * NF + f];
    W_comb[(size_t)(g0 + gl) * NF + f] = acc;
    if (f == 0) {
        float a2 = 0.f;
        for (int e = 0; e < NE; ++e) a2 += wih[gl][e] * b_emb[e];
        b_comb[g0 + gl] = a2 + b_ih[g0 + gl] + b_hh[g0 + gl];
    }
}

// Persistent LSTM, dense-A MFMA, REGISTER-DIRECT A-frags (R12 poll form).
// R15 structure (best ladder: 1340 -> R20 pre-sleep 1220us): 128 WGs =
// 4 batch-groups x 32 gate-slices; each WG owns 16 h-channels (4 n-tiles);
// part[] single-buffered (40KB pad-20), 2 barriers/step; R9-proven
// slab/tag protocol; waves 6,7 own the x k-tiles; s_sleep(8) pre-sleep
// before first poll (R20, +120us).
// R21 (this round, ONE variable): PUBLISH STORE MOVED AFTER bar2.
//   bar2 (__syncthreads) emits s_waitcnt vmcnt(0) — with the publish before
//   it, producer waves stalled ~600-900cy until the agent store was ACKed
//   at the IF$ coherence point, and THEN consumers slept 512cy more: drain
//   and sleep covered the same physical interval, serialized. Now the
//   epilogue computes v/gates/c/h and PACKS pkv in registers before bar2;
//   the store issues right after bar2, fire-and-forget, its flight
//   overlapping the consumers' pre-sleep. part[] safety unchanged (reads
//   complete before bar2; next writes ordered after bar2). Tag protocol,
//   slab mapping, poll loop: bit-identical.
// Exchange u32 {bf16hi<<16 | bf16lo&~3 | tag2}, tag2 = ((t+1)&3)^2.
__global__ __launch_bounds__(512, 1) void k_lstm(const float* __restrict__ x,
                                                 const float* __restrict__ W_hh,
                                                 const float* __restrict__ W_comb,
                                                 const float* __restrict__ b_comb,
                                                 u32* __restrict__ hbuf,
                                                 float* __restrict__ pooled) {
    const int wg = blockIdx.x;
    const int grp = wg & 3;            // 0..3
    const int slc = wg >> 2;           // 0..31 -> h-idx [16*slc, 16*slc+16)
    const int tid = threadIdx.x;
    const int lane = tid & 63, wave = tid >> 6;
    const int m4 = lane & 15;          // A row (batch) / B col fragment index
    const int qq = lane >> 4;          // quad

    const int mtn = (wave < 6) ? 2 : 3;
    int kts[3];
    kts[0] = (wave < 6) ? 2 * wave : 12 + 2 * (wave - 6);
    kts[1] = kts[0] + 1;
    kts[2] = (wave < 6) ? 0 : 16 + (wave - 6);

    // part single-buffered: [wave][n_loc(64)][b(pad20)] = 40KB
    __shared__ __align__(16) float part[8 * 64 * 20];
    __shared__ float bcl[64];

    // ---- B-fragments (split bf16, register-resident): 4 n-tiles x mtn ----
    F8 bhi[4][3], blo[4][3];
    #pragma unroll
    for (int nt = 0; nt < 4; ++nt) {
        // n_loc = nt*16 + m4; gate type = nt, h-channel = m4
        const int grow = nt * NH + slc * 16 + m4;
        #pragma unroll
        for (int k = 0; k < 3; ++k) {
            if (k < mtn) {
                const int kt = kts[k];
                const float* wp = (kt < 16)
                    ? W_hh   + (size_t)grow * NH + kt * 32 + qq * 8
                    : W_comb + (size_t)grow * NF + (kt - 16) * 32 + qq * 8;
                const float4 w0 = *(const float4*)wp;
                const float4 w1 = *(const float4*)(wp + 4);
                float wf[8] = {w0.x, w0.y, w0.z, w0.w, w1.x, w1.y, w1.z, w1.w};
                #pragma unroll
                for (int e = 0; e < 8; ++e) {
                    unsigned short hb = f2bf(wf[e]);
                    bhi[nt][k].u[e] = hb;
                    blo[nt][k].u[e] = f2bf(wf[e] - bf2f(hb));
                }
            }
        }
    }

    if (tid < 64) bcl[tid] = b_comb[(tid >> 4) * NH + slc * 16 + (tid & 15)];

    // ---- A-fragments in registers; t=0: h = 0 ----
    F8 ahi[3], alo[3];
    #pragma unroll
    for (int k = 0; k < 3; ++k) {
        ahi[k].s = (bf16x8){0, 0, 0, 0, 0, 0, 0, 0};
        alo[k].s = (bf16x8){0, 0, 0, 0, 0, 0, 0, 0};
    }
    float4 xpa = make_float4(0.f, 0.f, 0.f, 0.f), xpb = xpa;
    if (wave >= 6) {
        // x(0) direct -> frag; prefetch x(1). lane (m4,qq) owns row m4, cols
        // (wave-6)*32 + qq*8 .. +8 — exactly its A-fragment elements.
        const int xoff = (wave - 6) * 32 + qq * 8;
        const float* xr0 = x + ((size_t)(grp * RPG + m4) * TS + 0) * NF + xoff;
        const float4 a = ((const float4*)xr0)[0];
        const float4 b4 = ((const float4*)xr0)[1];
        float xf[8] = {a.x, a.y, a.z, a.w, b4.x, b4.y, b4.z, b4.w};
        #pragma unroll
        for (int e = 0; e < 8; ++e) {
            unsigned short hb = f2bf(xf[e]);
            ahi[2].u[e] = hb;
            alo[2].u[e] = f2bf(xf[e] - bf2f(hb));
        }
        const float* xr1 = x + ((size_t)(grp * RPG + m4) * TS + 1) * NF + xoff;
        xpa = ((const float4*)xr1)[0];
        xpb = ((const float4*)xr1)[1];
    }

    float c_reg = 0.f, hsum = 0.f;  // live on tid<256
    __syncthreads();  // bcl ready

    for (int t = 0; t < TS; ++t) {
        const bool last = (t + 1 == TS);
        const int p = t & 1;

        // ---- MFMA: own k-tiles, A-frags from registers, 3 split chains x 4 nt ----
        f32x4 acc[4][3];
        #pragma unroll
        for (int nt = 0; nt < 4; ++nt)
            #pragma unroll
            for (int c = 0; c < 3; ++c) acc[nt][c] = (f32x4){0.f, 0.f, 0.f, 0.f};
        #pragma unroll
        for (int k = 0; k < 3; ++k) {
            if (k < mtn) {
                const bf16x8 ah = ahi[k].s;
                const bf16x8 al = alo[k].s;
                #pragma unroll
                for (int nt = 0; nt < 4; ++nt) {
                    acc[nt][0] = __builtin_amdgcn_mfma_f32_16x16x32_bf16(ah, bhi[nt][k].s, acc[nt][0], 0, 0, 0);
                    acc[nt][1] = __builtin_amdgcn_mfma_f32_16x16x32_bf16(al, bhi[nt][k].s, acc[nt][1], 0, 0, 0);
                    acc[nt][2] = __builtin_amdgcn_mfma_f32_16x16x32_bf16(ah, blo[nt][k].s, acc[nt][2], 0, 0, 0);
                }
            }
        }
        #pragma unroll
        for (int nt = 0; nt < 4; ++nt) {
            const f32x4 a = acc[nt][0] + acc[nt][1] + acc[nt][2];
            *(float4*)&part[wave * 1280 + (nt * 16 + m4) * 20 + qq * 4] =
                make_float4(a.x, a.y, a.z, a.w);
        }
        __syncthreads();  // bar1: part ready

        const unsigned tg2 = (unsigned)(((t + 1) & 3) ^ 2);
        u32* const slab = hbuf + ((size_t)(p * NGRP + grp)) * 8192;

        // ---- epilogue (waves 0-3): v-sums + gates + c/h + PACK (no store) ----
        u32 pkv = 0u;
        if (tid < 256) {
            const int j = tid >> 4, b = tid & 15;
            float v[4];
            #pragma unroll
            for (int ty = 0; ty < 4; ++ty) {
                const int n_loc = ty * 16 + j;
                float s = bcl[n_loc];
                #pragma unroll
                for (int w = 0; w < 8; ++w) s += part[w * 1280 + n_loc * 20 + b];
                v[ty] = s;
            }
            const float iv = fast_sigmoid(v[0]);
            const float fv = fast_sigmoid(v[1]);
            const float gv = fast_tanh(v[2]);
            const float ov = fast_sigmoid(v[3]);
            c_reg = fv * c_reg + iv * gv;
            const float h = ov * fast_tanh(c_reg);
            hsum += h;
            const unsigned short hb = f2bf(h);
            const unsigned short lb = f2bf(h - bf2f(hb));
            pkv = ((u32)hb << 16) | ((u32)lb & 0xFFFCu) | tg2;
        }
        __syncthreads();  // bar2: part consumed; next-iter writes safe

        // ---- publish AFTER bar2: fire-and-forget; store flight overlaps
        //      the consumers' pre-sleep instead of stalling bar2's vmcnt(0)
        if (tid < 256 && !last) {
            // word = 16*hidx + batch, hidx = 16*slc + j -> slc*256 + tid
            __hip_atomic_store(&slab[slc * 256 + tid], pkv,
                               __ATOMIC_RELAXED, __HIP_MEMORY_SCOPE_AGENT);
        }

        // ---- per-wave poll of own frag words + in-register assembly ----
        if (!last) {
            // lane (m4,qq) needs slab[(kts[k]*4+qq)*128 + j*16 + m4], j=0..7, k=0,1
            const u32* b0 = slab + (kts[0] * 4 + qq) * 128 + m4;
            const u32* b1 = slab + (kts[1] * 4 + qq) * 128 + m4;
            u32 wd[16];
            // R20: calibrated pre-sleep (~512cy) — now also covers the
            // in-flight publish stores issued just above.
            __builtin_amdgcn_s_sleep(8);
            #pragma unroll
            for (int j = 0; j < 8; ++j) wd[j] = aload(b0 + j * 16);
            #pragma unroll
            for (int j = 0; j < 8; ++j) wd[8 + j] = aload(b1 + j * 16);
            int guard = 0;
            for (;;) {
                u32 bad = 0;
                #pragma unroll
                for (int i = 0; i < 16; ++i) bad |= (wd[i] & 3) ^ tg2;
                if (bad == 0) break;
                // near-hot spin: the reload round trip (~700cy) IS the
                // backoff; tiny sleeps only damp poll storms
                if (guard < 16)      __builtin_amdgcn_s_sleep(1);
                else if (guard < 64) __builtin_amdgcn_s_sleep(2);
                else                 __builtin_amdgcn_s_sleep(4);
                #pragma unroll
                for (int j = 0; j < 8; ++j) wd[j] = aload(b0 + j * 16);
                #pragma unroll
                for (int j = 0; j < 8; ++j) wd[8 + j] = aload(b1 + j * 16);
                if (++guard > (1 << 20)) break;  // anti-hang escape
            }
            #pragma unroll
            for (int j = 0; j < 8; ++j) {
                ahi[0].u[j] = (unsigned short)(wd[j] >> 16);
                alo[0].u[j] = (unsigned short)(wd[j] & 0xFFFCu);
                ahi[1].u[j] = (unsigned short)(wd[8 + j] >> 16);
                alo[1].u[j] = (unsigned short)(wd[8 + j] & 0xFFFCu);
            }
            // waves 6,7: x(t+1) frag from prefetch; prefetch x(t+2)
            if (wave >= 6) {
                const int xoff = (wave - 6) * 32 + qq * 8;
                float xf[8] = {xpa.x, xpa.y, xpa.z, xpa.w, xpb.x, xpb.y, xpb.z, xpb.w};
                #pragma unroll
                for (int e = 0; e < 8; ++e) {
                    unsigned short hb = f2bf(xf[e]);
                    ahi[2].u[e] = hb;
                    alo[2].u[e] = f2bf(xf[e] - bf2f(hb));
                }
                if (t + 2 < TS) {
                    const float* xr = x + ((size_t)(grp * RPG + m4) * TS + (t + 2)) * NF + xoff;
                    xpa = ((const float4*)xr)[0];
                    xpb = ((const float4*)xr)[1];
                }
            }
        }
        // no trailing barrier: A-frags are wave-private registers
    }

    if (tid < 256) {
        const int j = tid >> 4, b = tid & 15;
        pooled[(size_t)(grp * RPG + b) * NH + slc * 16 + j] = hsum * (1.f / TS);
    }
}

// out[b][o] = pooled[b]·W_fc[o] + b_fc[o]
__global__ __launch_bounds__(256) void k_fc(const float* __restrict__ pooled,
                                            const float* __restrict__ W_fc,
                                            const float* __restrict__ b_fc,
                                            float* __restrict__ out) {
    __shared__ float pl[2][NH];
    const int b0 = blockIdx.x * 2;
    for (int i = threadIdx.x; i < 2 * NH; i += 256)
        pl[i >> 9][i & 511] = pooled[(size_t)b0 * NH + i];
    __syncthreads();
    const int o = threadIdx.x & 127, bl = threadIdx.x >> 7;
    const float* wr = W_fc + (size_t)o * NH;
    float acc = 0.f;
    #pragma unroll 4
    for (int k = 0; k < NH; k += 4) {
        const float4 wv = *(const float4*)&wr[k];
        acc += pl[bl][k] * wv.x + pl[bl][k + 1] * wv.y +
               pl[bl][k + 2] * wv.z + pl[bl][k + 3] * wv.w;
    }
    out[(size_t)(b0 + bl) * NO + o] = acc + b_fc[o];
}

extern "C" void kernel_launch(void* const* d_in, const int* in_sizes, int n_in,
                              void* d_out, int out_size, void* d_ws, size_t ws_size,
                              hipStream_t stream) {
    const float* x     = (const float*)d_in[0];
    const float* W_emb = (const float*)d_in[1];
    const float* b_emb = (const float*)d_in[2];
    const float* W_ih  = (const float*)d_in[3];
    const float* W_hh  = (const float*)d_in[4];
    const float* b_ih  = (const float*)d_in[5];
    const float* b_hh  = (const float*)d_in[6];
    const float* W_fc  = (const float*)d_in[7];
    const float* b_fc  = (const float*)d_in[8];
    float* out = (float*)d_out;
    float* ws  = (float*)d_ws;

    float* W_comb = ws + OFF_WCOMB;
    float* b_comb = ws + OFF_BCOMB;
    u32*   hbuf   = (u32*)(ws + OFF_HBUF);
    float* pooled = ws + OFF_POOL;

    hipLaunchKernelGGL(k_wcomb, dim3(512), dim3(256), 0, stream,
                       W_emb, b_emb, W_ih, b_ih, b_hh, W_comb, b_comb);
    hipLaunchKernelGGL(k_lstm,  dim3(128), dim3(512), 0, stream,
                       x, W_hh, W_comb, b_comb, hbuf, pooled);
    hipLaunchKernelGGL(k_fc,    dim3(32),  dim3(256), 0, stream,
                       pooled, W_fc, b_fc, out);
}

// Round 10
// 1259.907 us; speedup vs baseline: 1.0314x; 1.0314x over previous
//
#include <hip/hip_runtime.h>
#include <math.h>

#define TS 512
#define NB 64
#define NF 64
#define NE 256
#define NH 512
#define NO 128

#define NGRP 4     // batch groups (16 rows each)
#define NSLC 32    // h-slices per group (16 h-idx each)  [R15 structure]
#define RPG  16    // rows per group (dense MFMA A)

// ws layout (float words)
#define OFF_WCOMB 0        // 2048*64
#define OFF_BCOMB 131072   // 2048
#define OFF_HBUF  133120   // u32[2][4][512h][16b] tagged h words = 65536
#define OFF_POOL  198656   // 64*512

typedef short bf16x8 __attribute__((ext_vector_type(8)));
typedef float f32x4 __attribute__((ext_vector_type(4)));
typedef unsigned long long u64;
typedef unsigned int u32;

union F8 { bf16x8 s; unsigned short u[8]; };

__device__ __forceinline__ unsigned short f2bf(float f) {
    unsigned u = __float_as_uint(f);
    u += 0x7fffu + ((u >> 16) & 1u);
    return (unsigned short)(u >> 16);
}
__device__ __forceinline__ float bf2f(unsigned short h) {
    return __uint_as_float(((unsigned)h) << 16);
}
__device__ __forceinline__ float fast_sigmoid(float v) {
    return 1.f / (1.f + __expf(-v));
}
__device__ __forceinline__ float fast_tanh(float v) {
    return 1.f - 2.f / (1.f + __expf(2.f * v));
}
__device__ __forceinline__ u32 aload(const u32* p) {
    return __hip_atomic_load(p, __ATOMIC_RELAXED, __HIP_MEMORY_SCOPE_AGENT);
}

// W_comb[g][f] = sum_e W_ih[g][e] * W_emb[e][f];  b_comb[g] = W_ih[g]·b_emb + b_ih[g] + b_hh[g]
__global__ __launch_bounds__(256) void k_wcomb(const float* __restrict__ W_emb,
                                               const float* __restrict__ b_emb,
                                               const float* __restrict__ W_ih,
                                               const float* __restrict__ b_ih,
                                               const float* __restrict__ b_hh,
                                               float* __restrict__ W_comb,
                                               float* __restrict__ b_comb) {
    __shared__ float wih[4][NE];
    int g0 = blockIdx.x * 4;
    for (int i = threadIdx.x; i < 4 * NE; i += 256)
        wih[i >> 8][i & 255] = W_ih[(size_t)g0 * NE + i];
    __syncthreads();
    int gl = threadIdx.x >> 6, f = threadIdx.x & 63;
    float acc = 0.f;
    for (int e = 0; e < NE; ++e) acc += wih[gl][e] * W_emb[e * NF + f];
    W_comb[(size_t)(g0 + gl) * NF + f] = acc;
    if (f == 0) {
        float a2 = 0.f;
        for (int e = 0; e < NE; ++e) a2 += wih[gl][e] * b_emb[e];
        b_comb[g0 + gl] = a2 + b_ih[g0 + gl] + b_hh[g0 + gl];
    }
}

// Persistent LSTM, dense-A MFMA, REGISTER-DIRECT A-frags.
// R20 base (best verified: 1220us): 128 WGs = 4 batch-groups x 32 gate-
// slices; 16 h-channels/WG (4 n-tiles); part[] single-buffered (40KB
// pad-20), 2 barriers/step; R9-proven slab/tag protocol; waves 6,7 own the
// x k-tiles; s_sleep(8) pre-sleep; publish INSIDE epilogue before bar2
// (R21's publish-after-bar2 was neutral-to-worse + outlier-prone: reverted).
// R22 (this round): SPLIT-TILE PIPELINED POLL. The ~2400cy/step gap over
// the serial-term sum is producer-skew convoy: a wave's 2 k-tiles come from
// 2 different producer WGs, and the joint 16-word poll waits for the MAX of
// the two. Now the MFMA block lives in the poll phase, per k-tile:
//   poll tile0 -> assemble -> k=0 MFMAs (12)   [overlaps tile1's lag]
//   poll tile1 -> assemble -> k=1 MFMAs (12)
//   waves 6,7: x convert -> k=2 MFMAs -> prefetch
// Loop top is just {part-write, bar1, epilogue+publish, bar2}. Math
// identical: acc carried across the loop boundary; t=0 pre-computed with
// h=0 (only x MFMAs contribute). Protocol bit-identical to R20.
// Exchange u32 {bf16hi<<16 | bf16lo&~3 | tag2}, tag2 = ((t+1)&3)^2.
__global__ __launch_bounds__(512, 1) void k_lstm(const float* __restrict__ x,
                                                 const float* __restrict__ W_hh,
                                                 const float* __restrict__ W_comb,
                                                 const float* __restrict__ b_comb,
                                                 u32* __restrict__ hbuf,
                                                 float* __restrict__ pooled) {
    const int wg = blockIdx.x;
    const int grp = wg & 3;            // 0..3
    const int slc = wg >> 2;           // 0..31 -> h-idx [16*slc, 16*slc+16)
    const int tid = threadIdx.x;
    const int lane = tid & 63, wave = tid >> 6;
    const int m4 = lane & 15;          // A row (batch) / B col fragment index
    const int qq = lane >> 4;          // quad

    const int mtn = (wave < 6) ? 2 : 3;
    int kts[3];
    kts[0] = (wave < 6) ? 2 * wave : 12 + 2 * (wave - 6);
    kts[1] = kts[0] + 1;
    kts[2] = (wave < 6) ? 0 : 16 + (wave - 6);

    // part single-buffered: [wave][n_loc(64)][b(pad20)] = 40KB
    __shared__ __align__(16) float part[8 * 64 * 20];
    __shared__ float bcl[64];

    // ---- B-fragments (split bf16, register-resident): 4 n-tiles x mtn ----
    F8 bhi[4][3], blo[4][3];
    #pragma unroll
    for (int nt = 0; nt < 4; ++nt) {
        // n_loc = nt*16 + m4; gate type = nt, h-channel = m4
        const int grow = nt * NH + slc * 16 + m4;
        #pragma unroll
        for (int k = 0; k < 3; ++k) {
            if (k < mtn) {
                const int kt = kts[k];
                const float* wp = (kt < 16)
                    ? W_hh   + (size_t)grow * NH + kt * 32 + qq * 8
                    : W_comb + (size_t)grow * NF + (kt - 16) * 32 + qq * 8;
                const float4 w0 = *(const float4*)wp;
                const float4 w1 = *(const float4*)(wp + 4);
                float wf[8] = {w0.x, w0.y, w0.z, w0.w, w1.x, w1.y, w1.z, w1.w};
                #pragma unroll
                for (int e = 0; e < 8; ++e) {
                    unsigned short hb = f2bf(wf[e]);
                    bhi[nt][k].u[e] = hb;
                    blo[nt][k].u[e] = f2bf(wf[e] - bf2f(hb));
                }
            }
        }
    }

    if (tid < 64) bcl[tid] = b_comb[(tid >> 4) * NH + slc * 16 + (tid & 15)];

    // ---- A-fragments in registers; t=0: h = 0 ----
    F8 ahi[3], alo[3];
    #pragma unroll
    for (int k = 0; k < 3; ++k) {
        ahi[k].s = (bf16x8){0, 0, 0, 0, 0, 0, 0, 0};
        alo[k].s = (bf16x8){0, 0, 0, 0, 0, 0, 0, 0};
    }
    float4 xpa = make_float4(0.f, 0.f, 0.f, 0.f), xpb = xpa;
    if (wave >= 6) {
        // x(0) direct -> frag; prefetch x(1). lane (m4,qq) owns row m4, cols
        // (wave-6)*32 + qq*8 .. +8 — exactly its A-fragment elements.
        const int xoff = (wave - 6) * 32 + qq * 8;
        const float* xr0 = x + ((size_t)(grp * RPG + m4) * TS + 0) * NF + xoff;
        const float4 a = ((const float4*)xr0)[0];
        const float4 b4 = ((const float4*)xr0)[1];
        float xf[8] = {a.x, a.y, a.z, a.w, b4.x, b4.y, b4.z, b4.w};
        #pragma unroll
        for (int e = 0; e < 8; ++e) {
            unsigned short hb = f2bf(xf[e]);
            ahi[2].u[e] = hb;
            alo[2].u[e] = f2bf(xf[e] - bf2f(hb));
        }
        const float* xr1 = x + ((size_t)(grp * RPG + m4) * TS + 1) * NF + xoff;
        xpa = ((const float4*)xr1)[0];
        xpb = ((const float4*)xr1)[1];
    }

    // ---- acc(t=0): h = 0 -> only x MFMAs contribute (waves 6,7) ----
    f32x4 acc[4][3];
    #pragma unroll
    for (int nt = 0; nt < 4; ++nt)
        #pragma unroll
        for (int c = 0; c < 3; ++c) acc[nt][c] = (f32x4){0.f, 0.f, 0.f, 0.f};
    if (wave >= 6) {
        #pragma unroll
        for (int nt = 0; nt < 4; ++nt) {
            acc[nt][0] = __builtin_amdgcn_mfma_f32_16x16x32_bf16(ahi[2].s, bhi[nt][2].s, acc[nt][0], 0, 0, 0);
            acc[nt][1] = __builtin_amdgcn_mfma_f32_16x16x32_bf16(alo[2].s, bhi[nt][2].s, acc[nt][1], 0, 0, 0);
            acc[nt][2] = __builtin_amdgcn_mfma_f32_16x16x32_bf16(ahi[2].s, blo[nt][2].s, acc[nt][2], 0, 0, 0);
        }
    }

    float c_reg = 0.f, hsum = 0.f;  // live on tid<256
    __syncthreads();  // bcl ready

    for (int t = 0; t < TS; ++t) {
        const bool last = (t + 1 == TS);
        const int p = t & 1;

        // ---- part write from acc (computed at end of previous iteration) ----
        #pragma unroll
        for (int nt = 0; nt < 4; ++nt) {
            const f32x4 a = acc[nt][0] + acc[nt][1] + acc[nt][2];
            *(float4*)&part[wave * 1280 + (nt * 16 + m4) * 20 + qq * 4] =
                make_float4(a.x, a.y, a.z, a.w);
        }
        __syncthreads();  // bar1: part ready

        const unsigned tg2 = (unsigned)(((t + 1) & 3) ^ 2);
        u32* const slab = hbuf + ((size_t)(p * NGRP + grp)) * 8192;

        // ---- fused epilogue + publish (waves 0-3), R20-exact ----
        if (tid < 256) {
            const int j = tid >> 4, b = tid & 15;
            float v[4];
            #pragma unroll
            for (int ty = 0; ty < 4; ++ty) {
                const int n_loc = ty * 16 + j;
                float s = bcl[n_loc];
                #pragma unroll
                for (int w = 0; w < 8; ++w) s += part[w * 1280 + n_loc * 20 + b];
                v[ty] = s;
            }
            const float iv = fast_sigmoid(v[0]);
            const float fv = fast_sigmoid(v[1]);
            const float gv = fast_tanh(v[2]);
            const float ov = fast_sigmoid(v[3]);
            c_reg = fv * c_reg + iv * gv;
            const float h = ov * fast_tanh(c_reg);
            hsum += h;
            if (!last) {
                const unsigned short hb = f2bf(h);
                const unsigned short lb = f2bf(h - bf2f(hb));
                const u32 pk = ((u32)hb << 16) | ((u32)lb & 0xFFFCu) | tg2;
                // word = 16*hidx + batch, hidx = 16*slc + j -> slc*256 + tid
                __hip_atomic_store(&slab[slc * 256 + tid], pk,
                                   __ATOMIC_RELAXED, __HIP_MEMORY_SCOPE_AGENT);
            }
        }
        __syncthreads();  // bar2: part consumed; next-iter writes safe

        // ---- pipelined poll + MFMA for t+1 ----
        if (!last) {
            const u32* b0 = slab + (kts[0] * 4 + qq) * 128 + m4;
            const u32* b1 = slab + (kts[1] * 4 + qq) * 128 + m4;
            u32 wd[8];

            #pragma unroll
            for (int nt = 0; nt < 4; ++nt)
                #pragma unroll
                for (int c = 0; c < 3; ++c) acc[nt][c] = (f32x4){0.f, 0.f, 0.f, 0.f};

            // R20 calibrated pre-sleep (~512cy): producers' agent stores
            // need ~500-700cy to reach the coherence point.
            __builtin_amdgcn_s_sleep(8);

            // -- tile 0: poll 8 words, assemble, run k=0 MFMAs --
            #pragma unroll
            for (int j = 0; j < 8; ++j) wd[j] = aload(b0 + j * 16);
            int guard = 0;
            for (;;) {
                u32 bad = 0;
                #pragma unroll
                for (int i = 0; i < 8; ++i) bad |= (wd[i] & 3) ^ tg2;
                if (bad == 0) break;
                if (guard < 16)      __builtin_amdgcn_s_sleep(1);
                else if (guard < 64) __builtin_amdgcn_s_sleep(2);
                else                 __builtin_amdgcn_s_sleep(4);
                #pragma unroll
                for (int j = 0; j < 8; ++j) wd[j] = aload(b0 + j * 16);
                if (++guard > (1 << 20)) break;  // anti-hang escape
            }
            #pragma unroll
            for (int j = 0; j < 8; ++j) {
                ahi[0].u[j] = (unsigned short)(wd[j] >> 16);
                alo[0].u[j] = (unsigned short)(wd[j] & 0xFFFCu);
            }
            #pragma unroll
            for (int nt = 0; nt < 4; ++nt) {
                acc[nt][0] = __builtin_amdgcn_mfma_f32_16x16x32_bf16(ahi[0].s, bhi[nt][0].s, acc[nt][0], 0, 0, 0);
                acc[nt][1] = __builtin_amdgcn_mfma_f32_16x16x32_bf16(alo[0].s, bhi[nt][0].s, acc[nt][1], 0, 0, 0);
                acc[nt][2] = __builtin_amdgcn_mfma_f32_16x16x32_bf16(ahi[0].s, blo[nt][0].s, acc[nt][2], 0, 0, 0);
            }

            // -- tile 1: poll 8 words (likely landed during k=0), k=1 MFMAs --
            #pragma unroll
            for (int j = 0; j < 8; ++j) wd[j] = aload(b1 + j * 16);
            guard = 0;
            for (;;) {
                u32 bad = 0;
                #pragma unroll
                for (int i = 0; i < 8; ++i) bad |= (wd[i] & 3) ^ tg2;
                if (bad == 0) break;
                if (guard < 16)      __builtin_amdgcn_s_sleep(1);
                else if (guard < 64) __builtin_amdgcn_s_sleep(2);
                else                 __builtin_amdgcn_s_sleep(4);
                #pragma unroll
                for (int j = 0; j < 8; ++j) wd[j] = aload(b1 + j * 16);
                if (++guard > (1 << 20)) break;  // anti-hang escape
            }
            #pragma unroll
            for (int j = 0; j < 8; ++j) {
                ahi[1].u[j] = (unsigned short)(wd[j] >> 16);
                alo[1].u[j] = (unsigned short)(wd[j] & 0xFFFCu);
            }
            #pragma unroll
            for (int nt = 0; nt < 4; ++nt) {
                acc[nt][0] = __builtin_amdgcn_mfma_f32_16x16x32_bf16(ahi[1].s, bhi[nt][1].s, acc[nt][0], 0, 0, 0);
                acc[nt][1] = __builtin_amdgcn_mfma_f32_16x16x32_bf16(alo[1].s, bhi[nt][1].s, acc[nt][1], 0, 0, 0);
                acc[nt][2] = __builtin_amdgcn_mfma_f32_16x16x32_bf16(ahi[1].s, blo[nt][1].s, acc[nt][2], 0, 0, 0);
            }

            // -- waves 6,7: x(t+1) convert, k=2 MFMAs, prefetch x(t+2) --
            if (wave >= 6) {
                const int xoff = (wave - 6) * 32 + qq * 8;
                float xf[8] = {xpa.x, xpa.y, xpa.z, xpa.w, xpb.x, xpb.y, xpb.z, xpb.w};
                #pragma unroll
                for (int e = 0; e < 8; ++e) {
                    unsigned short hb = f2bf(xf[e]);
                    ahi[2].u[e] = hb;
                    alo[2].u[e] = f2bf(xf[e] - bf2f(hb));
                }
                #pragma unroll
                for (int nt = 0; nt < 4; ++nt) {
                    acc[nt][0] = __builtin_amdgcn_mfma_f32_16x16x32_bf16(ahi[2].s, bhi[nt][2].s, acc[nt][0], 0, 0, 0);
                    acc[nt][1] = __builtin_amdgcn_mfma_f32_16x16x32_bf16(alo[2].s, bhi[nt][2].s, acc[nt][1], 0, 0, 0);
                    acc[nt][2] = __builtin_amdgcn_mfma_f32_16x16x32_bf16(ahi[2].s, blo[nt][2].s, acc[nt][2], 0, 0, 0);
                }
                if (t + 2 < TS) {
                    const float* xr = x + ((size_t)(grp * RPG + m4) * TS + (t + 2)) * NF + xoff;
                    xpa = ((const float4*)xr)[0];
                    xpb = ((const float4*)xr)[1];
                }
            }
        }
        // no trailing barrier: A-frags/acc are wave-private registers
    }

    if (tid < 256) {
        const int j = tid >> 4, b = tid & 15;
        pooled[(size_t)(grp * RPG + b) * NH + slc * 16 + j] = hsum * (1.f / TS);
    }
}

// out[b][o] = pooled[b]·W_fc[o] + b_fc[o]
__global__ __launch_bounds__(256) void k_fc(const float* __restrict__ pooled,
                                            const float* __restrict__ W_fc,
                                            const float* __restrict__ b_fc,
                                            float* __restrict__ out) {
    __shared__ float pl[2][NH];
    const int b0 = blockIdx.x * 2;
    for (int i = threadIdx.x; i < 2 * NH; i += 256)
        pl[i >> 9][i & 511] = pooled[(size_t)b0 * NH + i];
    __syncthreads();
    const int o = threadIdx.x & 127, bl = threadIdx.x >> 7;
    const float* wr = W_fc + (size_t)o * NH;
    float acc = 0.f;
    #pragma unroll 4
    for (int k = 0; k < NH; k += 4) {
        const float4 wv = *(const float4*)&wr[k];
        acc += pl[bl][k] * wv.x + pl[bl][k + 1] * wv.y +
               pl[bl][k + 2] * wv.z + pl[bl][k + 3] * wv.w;
    }
    out[(size_t)(b0 + bl) * NO + o] = acc + b_fc[o];
}

extern "C" void kernel_launch(void* const* d_in, const int* in_sizes, int n_in,
                              void* d_out, int out_size, void* d_ws, size_t ws_size,
                              hipStream_t stream) {
    const float* x     = (const float*)d_in[0];
    const float* W_emb = (const float*)d_in[1];
    const float* b_emb = (const float*)d_in[2];
    const float* W_ih  = (const float*)d_in[3];
    const float* W_hh  = (const float*)d_in[4];
    const float* b_ih  = (const float*)d_in[5];
    const float* b_hh  = (const float*)d_in[6];
    const float* W_fc  = (const float*)d_in[7];
    const float* b_fc  = (const float*)d_in[8];
    float* out = (float*)d_out;
    float* ws  = (float*)d_ws;

    float* W_comb = ws + OFF_WCOMB;
    float* b_comb = ws + OFF_BCOMB;
    u32*   hbuf   = (u32*)(ws + OFF_HBUF);
    float* pooled = ws + OFF_POOL;

    hipLaunchKernelGGL(k_wcomb, dim3(512), dim3(256), 0, stream,
                       W_emb, b_emb, W_ih, b_ih, b_hh, W_comb, b_comb);
    hipLaunchKernelGGL(k_lstm,  dim3(128), dim3(512), 0, stream,
                       x, W_hh, W_comb, b_comb, hbuf, pooled);
    hipLaunchKernelGGL(k_fc,    dim3(32),  dim3(256), 0, stream,
                       pooled, W_fc, b_fc, out);
}

// Round 11
// 1237.799 us; speedup vs baseline: 1.0499x; 1.0179x over previous
//
#include <hip/hip_runtime.h>
#include <math.h>

#define TS 512
#define NB 64
#define NF 64
#define NE 256
#define NH 512
#define NO 128

#define NGRP 4     // batch groups (16 rows each)
#define NSLC 32    // h-slices per group (16 h-idx each)  [R15 structure]
#define RPG  16    // rows per group (dense MFMA A)

// ws layout (float words)
#define OFF_WCOMB 0        // 2048*64
#define OFF_BCOMB 131072   // 2048
#define OFF_HBUF  133120   // u32[2][4][512h][16b] tagged h words = 65536
#define OFF_POOL  198656   // 64*512

typedef short bf16x8 __attribute__((ext_vector_type(8)));
typedef float f32x4 __attribute__((ext_vector_type(4)));
typedef unsigned long long u64;
typedef unsigned int u32;

union F8 { bf16x8 s; unsigned short u[8]; };

__device__ __forceinline__ unsigned short f2bf(float f) {
    unsigned u = __float_as_uint(f);
    u += 0x7fffu + ((u >> 16) & 1u);
    return (unsigned short)(u >> 16);
}
__device__ __forceinline__ float bf2f(unsigned short h) {
    return __uint_as_float(((unsigned)h) << 16);
}
__device__ __forceinline__ float fast_sigmoid(float v) {
    return 1.f / (1.f + __expf(-v));
}
__device__ __forceinline__ float fast_tanh(float v) {
    return 1.f - 2.f / (1.f + __expf(2.f * v));
}
__device__ __forceinline__ u32 aload(const u32* p) {
    return __hip_atomic_load(p, __ATOMIC_RELAXED, __HIP_MEMORY_SCOPE_AGENT);
}

// W_comb[g][f] = sum_e W_ih[g][e] * W_emb[e][f];  b_comb[g] = W_ih[g]·b_emb + b_ih[g] + b_hh[g]
__global__ __launch_bounds__(256) void k_wcomb(const float* __restrict__ W_emb,
                                               const float* __restrict__ b_emb,
                                               const float* __restrict__ W_ih,
                                               const float* __restrict__ b_ih,
                                               const float* __restrict__ b_hh,
                                               float* __restrict__ W_comb,
                                               float* __restrict__ b_comb) {
    __shared__ float wih[4][NE];
    int g0 = blockIdx.x * 4;
    for (int i = threadIdx.x; i < 4 * NE; i += 256)
        wih[i >> 8][i & 255] = W_ih[(size_t)g0 * NE + i];
    __syncthreads();
    int gl = threadIdx.x >> 6, f = threadIdx.x & 63;
    float acc = 0.f;
    for (int e = 0; e < NE; ++e) acc += wih[gl][e] * W_emb[e * NF + f];
    W_comb[(size_t)(g0 + gl) * NF + f] = acc;
    if (f == 0) {
        float a2 = 0.f;
        for (int e = 0; e < NE; ++e) a2 += wih[gl][e] * b_emb[e];
        b_comb[g0 + gl] = a2 + b_ih[g0 + gl] + b_hh[g0 + gl];
    }
}

// Persistent LSTM, dense-A MFMA, REGISTER-DIRECT A-frags.
// Ladder: R15 fan-out 1340 -> R20 pre-sleep 1220 -> R22 pipelined poll 1184.
// Structure: 128 WGs = 4 batch-groups x 32 gate-slices; 16 h-channels/WG
// (4 n-tiles); part[] single-buffered (40KB pad-20), 2 barriers/step;
// R9-proven slab/tag protocol; publish inside epilogue before bar2;
// split-tile pipelined poll (poll tile0 -> k0 MFMAs -> poll tile1 -> k1).
// R23 (this round, ONE variable): HOIST waves 6,7's x-work (convert x(t+1),
// k=2 MFMAs, x(t+2) prefetch issue — all poll-independent, register-only)
// from AFTER the polls to BEFORE the pre-sleep, and shorten their sleep to
// s_sleep(4): the x-work itself consumes ~250cy of the ~512cy calibrated
// visibility wait, so time-to-first-poll stays ~constant for all waves
// (no early-poll contention), while waves 6,7's post-detect path — the
// step's critical tail that bar1 waits on — shrinks to match waves 0-5.
// Exchange u32 {bf16hi<<16 | bf16lo&~3 | tag2}, tag2 = ((t+1)&3)^2.
__global__ __launch_bounds__(512, 1) void k_lstm(const float* __restrict__ x,
                                                 const float* __restrict__ W_hh,
                                                 const float* __restrict__ W_comb,
                                                 const float* __restrict__ b_comb,
                                                 u32* __restrict__ hbuf,
                                                 float* __restrict__ pooled) {
    const int wg = blockIdx.x;
    const int grp = wg & 3;            // 0..3
    const int slc = wg >> 2;           // 0..31 -> h-idx [16*slc, 16*slc+16)
    const int tid = threadIdx.x;
    const int lane = tid & 63, wave = tid >> 6;
    const int m4 = lane & 15;          // A row (batch) / B col fragment index
    const int qq = lane >> 4;          // quad

    const int mtn = (wave < 6) ? 2 : 3;
    int kts[3];
    kts[0] = (wave < 6) ? 2 * wave : 12 + 2 * (wave - 6);
    kts[1] = kts[0] + 1;
    kts[2] = (wave < 6) ? 0 : 16 + (wave - 6);

    // part single-buffered: [wave][n_loc(64)][b(pad20)] = 40KB
    __shared__ __align__(16) float part[8 * 64 * 20];
    __shared__ float bcl[64];

    // ---- B-fragments (split bf16, register-resident): 4 n-tiles x mtn ----
    F8 bhi[4][3], blo[4][3];
    #pragma unroll
    for (int nt = 0; nt < 4; ++nt) {
        // n_loc = nt*16 + m4; gate type = nt, h-channel = m4
        const int grow = nt * NH + slc * 16 + m4;
        #pragma unroll
        for (int k = 0; k < 3; ++k) {
            if (k < mtn) {
                const int kt = kts[k];
                const float* wp = (kt < 16)
                    ? W_hh   + (size_t)grow * NH + kt * 32 + qq * 8
                    : W_comb + (size_t)grow * NF + (kt - 16) * 32 + qq * 8;
                const float4 w0 = *(const float4*)wp;
                const float4 w1 = *(const float4*)(wp + 4);
                float wf[8] = {w0.x, w0.y, w0.z, w0.w, w1.x, w1.y, w1.z, w1.w};
                #pragma unroll
                for (int e = 0; e < 8; ++e) {
                    unsigned short hb = f2bf(wf[e]);
                    bhi[nt][k].u[e] = hb;
                    blo[nt][k].u[e] = f2bf(wf[e] - bf2f(hb));
                }
            }
        }
    }

    if (tid < 64) bcl[tid] = b_comb[(tid >> 4) * NH + slc * 16 + (tid & 15)];

    // ---- A-fragments in registers; t=0: h = 0 ----
    F8 ahi[3], alo[3];
    #pragma unroll
    for (int k = 0; k < 3; ++k) {
        ahi[k].s = (bf16x8){0, 0, 0, 0, 0, 0, 0, 0};
        alo[k].s = (bf16x8){0, 0, 0, 0, 0, 0, 0, 0};
    }
    float4 xpa = make_float4(0.f, 0.f, 0.f, 0.f), xpb = xpa;
    if (wave >= 6) {
        // x(0) direct -> frag; prefetch x(1). lane (m4,qq) owns row m4, cols
        // (wave-6)*32 + qq*8 .. +8 — exactly its A-fragment elements.
        const int xoff = (wave - 6) * 32 + qq * 8;
        const float* xr0 = x + ((size_t)(grp * RPG + m4) * TS + 0) * NF + xoff;
        const float4 a = ((const float4*)xr0)[0];
        const float4 b4 = ((const float4*)xr0)[1];
        float xf[8] = {a.x, a.y, a.z, a.w, b4.x, b4.y, b4.z, b4.w};
        #pragma unroll
        for (int e = 0; e < 8; ++e) {
            unsigned short hb = f2bf(xf[e]);
            ahi[2].u[e] = hb;
            alo[2].u[e] = f2bf(xf[e] - bf2f(hb));
        }
        const float* xr1 = x + ((size_t)(grp * RPG + m4) * TS + 1) * NF + xoff;
        xpa = ((const float4*)xr1)[0];
        xpb = ((const float4*)xr1)[1];
    }

    // ---- acc(t=0): h = 0 -> only x MFMAs contribute (waves 6,7) ----
    f32x4 acc[4][3];
    #pragma unroll
    for (int nt = 0; nt < 4; ++nt)
        #pragma unroll
        for (int c = 0; c < 3; ++c) acc[nt][c] = (f32x4){0.f, 0.f, 0.f, 0.f};
    if (wave >= 6) {
        #pragma unroll
        for (int nt = 0; nt < 4; ++nt) {
            acc[nt][0] = __builtin_amdgcn_mfma_f32_16x16x32_bf16(ahi[2].s, bhi[nt][2].s, acc[nt][0], 0, 0, 0);
            acc[nt][1] = __builtin_amdgcn_mfma_f32_16x16x32_bf16(alo[2].s, bhi[nt][2].s, acc[nt][1], 0, 0, 0);
            acc[nt][2] = __builtin_amdgcn_mfma_f32_16x16x32_bf16(ahi[2].s, blo[nt][2].s, acc[nt][2], 0, 0, 0);
        }
    }

    float c_reg = 0.f, hsum = 0.f;  // live on tid<256
    __syncthreads();  // bcl ready

    for (int t = 0; t < TS; ++t) {
        const bool last = (t + 1 == TS);
        const int p = t & 1;

        // ---- part write from acc (computed at end of previous iteration) ----
        #pragma unroll
        for (int nt = 0; nt < 4; ++nt) {
            const f32x4 a = acc[nt][0] + acc[nt][1] + acc[nt][2];
            *(float4*)&part[wave * 1280 + (nt * 16 + m4) * 20 + qq * 4] =
                make_float4(a.x, a.y, a.z, a.w);
        }
        __syncthreads();  // bar1: part ready

        const unsigned tg2 = (unsigned)(((t + 1) & 3) ^ 2);
        u32* const slab = hbuf + ((size_t)(p * NGRP + grp)) * 8192;

        // ---- fused epilogue + publish (waves 0-3), R20-exact ----
        if (tid < 256) {
            const int j = tid >> 4, b = tid & 15;
            float v[4];
            #pragma unroll
            for (int ty = 0; ty < 4; ++ty) {
                const int n_loc = ty * 16 + j;
                float s = bcl[n_loc];
                #pragma unroll
                for (int w = 0; w < 8; ++w) s += part[w * 1280 + n_loc * 20 + b];
                v[ty] = s;
            }
            const float iv = fast_sigmoid(v[0]);
            const float fv = fast_sigmoid(v[1]);
            const float gv = fast_tanh(v[2]);
            const float ov = fast_sigmoid(v[3]);
            c_reg = fv * c_reg + iv * gv;
            const float h = ov * fast_tanh(c_reg);
            hsum += h;
            if (!last) {
                const unsigned short hb = f2bf(h);
                const unsigned short lb = f2bf(h - bf2f(hb));
                const u32 pk = ((u32)hb << 16) | ((u32)lb & 0xFFFCu) | tg2;
                // word = 16*hidx + batch, hidx = 16*slc + j -> slc*256 + tid
                __hip_atomic_store(&slab[slc * 256 + tid], pk,
                                   __ATOMIC_RELAXED, __HIP_MEMORY_SCOPE_AGENT);
            }
        }
        __syncthreads();  // bar2: part consumed; next-iter writes safe

        // ---- pipelined poll + MFMA for t+1 ----
        if (!last) {
            const u32* b0 = slab + (kts[0] * 4 + qq) * 128 + m4;
            const u32* b1 = slab + (kts[1] * 4 + qq) * 128 + m4;
            u32 wd[8];

            #pragma unroll
            for (int nt = 0; nt < 4; ++nt)
                #pragma unroll
                for (int c = 0; c < 3; ++c) acc[nt][c] = (f32x4){0.f, 0.f, 0.f, 0.f};

            // R23: waves 6,7 do their poll-independent x-work FIRST — it
            // fills ~250cy of the calibrated visibility wait; their sleep is
            // shortened to keep time-to-first-poll ~equal across waves.
            if (wave >= 6) {
                const int xoff = (wave - 6) * 32 + qq * 8;
                float xf[8] = {xpa.x, xpa.y, xpa.z, xpa.w, xpb.x, xpb.y, xpb.z, xpb.w};
                #pragma unroll
                for (int e = 0; e < 8; ++e) {
                    unsigned short hb = f2bf(xf[e]);
                    ahi[2].u[e] = hb;
                    alo[2].u[e] = f2bf(xf[e] - bf2f(hb));
                }
                #pragma unroll
                for (int nt = 0; nt < 4; ++nt) {
                    acc[nt][0] = __builtin_amdgcn_mfma_f32_16x16x32_bf16(ahi[2].s, bhi[nt][2].s, acc[nt][0], 0, 0, 0);
                    acc[nt][1] = __builtin_amdgcn_mfma_f32_16x16x32_bf16(alo[2].s, bhi[nt][2].s, acc[nt][1], 0, 0, 0);
                    acc[nt][2] = __builtin_amdgcn_mfma_f32_16x16x32_bf16(ahi[2].s, blo[nt][2].s, acc[nt][2], 0, 0, 0);
                }
                if (t + 2 < TS) {
                    const float* xr = x + ((size_t)(grp * RPG + m4) * TS + (t + 2)) * NF + xoff;
                    xpa = ((const float4*)xr)[0];
                    xpb = ((const float4*)xr)[1];
                }
                __builtin_amdgcn_s_sleep(4);   // ~256cy: x-work covered the rest
            } else {
                __builtin_amdgcn_s_sleep(8);   // ~512cy calibrated wait (R20)
            }

            // -- tile 0: poll 8 words, assemble, run k=0 MFMAs --
            #pragma unroll
            for (int j = 0; j < 8; ++j) wd[j] = aload(b0 + j * 16);
            int guard = 0;
            for (;;) {
                u32 bad = 0;
                #pragma unroll
                for (int i = 0; i < 8; ++i) bad |= (wd[i] & 3) ^ tg2;
                if (bad == 0) break;
                if (guard < 16)      __builtin_amdgcn_s_sleep(1);
                else if (guard < 64) __builtin_amdgcn_s_sleep(2);
                else                 __builtin_amdgcn_s_sleep(4);
                #pragma unroll
                for (int j = 0; j < 8; ++j) wd[j] = aload(b0 + j * 16);
                if (++guard > (1 << 20)) break;  // anti-hang escape
            }
            #pragma unroll
            for (int j = 0; j < 8; ++j) {
                ahi[0].u[j] = (unsigned short)(wd[j] >> 16);
                alo[0].u[j] = (unsigned short)(wd[j] & 0xFFFCu);
            }
            #pragma unroll
            for (int nt = 0; nt < 4; ++nt) {
                acc[nt][0] = __builtin_amdgcn_mfma_f32_16x16x32_bf16(ahi[0].s, bhi[nt][0].s, acc[nt][0], 0, 0, 0);
                acc[nt][1] = __builtin_amdgcn_mfma_f32_16x16x32_bf16(alo[0].s, bhi[nt][0].s, acc[nt][1], 0, 0, 0);
                acc[nt][2] = __builtin_amdgcn_mfma_f32_16x16x32_bf16(ahi[0].s, blo[nt][0].s, acc[nt][2], 0, 0, 0);
            }

            // -- tile 1: poll 8 words (likely landed during k=0), k=1 MFMAs --
            #pragma unroll
            for (int j = 0; j < 8; ++j) wd[j] = aload(b1 + j * 16);
            guard = 0;
            for (;;) {
                u32 bad = 0;
                #pragma unroll
                for (int i = 0; i < 8; ++i) bad |= (wd[i] & 3) ^ tg2;
                if (bad == 0) break;
                if (guard < 16)      __builtin_amdgcn_s_sleep(1);
                else if (guard < 64) __builtin_amdgcn_s_sleep(2);
                else                 __builtin_amdgcn_s_sleep(4);
                #pragma unroll
                for (int j = 0; j < 8; ++j) wd[j] = aload(b1 + j * 16);
                if (++guard > (1 << 20)) break;  // anti-hang escape
            }
            #pragma unroll
            for (int j = 0; j < 8; ++j) {
                ahi[1].u[j] = (unsigned short)(wd[j] >> 16);
                alo[1].u[j] = (unsigned short)(wd[j] & 0xFFFCu);
            }
            #pragma unroll
            for (int nt = 0; nt < 4; ++nt) {
                acc[nt][0] = __builtin_amdgcn_mfma_f32_16x16x32_bf16(ahi[1].s, bhi[nt][1].s, acc[nt][0], 0, 0, 0);
                acc[nt][1] = __builtin_amdgcn_mfma_f32_16x16x32_bf16(alo[1].s, bhi[nt][1].s, acc[nt][1], 0, 0, 0);
                acc[nt][2] = __builtin_amdgcn_mfma_f32_16x16x32_bf16(ahi[1].s, blo[nt][1].s, acc[nt][2], 0, 0, 0);
            }
        }
        // no trailing barrier: A-frags/acc are wave-private registers
    }

    if (tid < 256) {
        const int j = tid >> 4, b = tid & 15;
        pooled[(size_t)(grp * RPG + b) * NH + slc * 16 + j] = hsum * (1.f / TS);
    }
}

// out[b][o] = pooled[b]·W_fc[o] + b_fc[o]
__global__ __launch_bounds__(256) void k_fc(const float* __restrict__ pooled,
                                            const float* __restrict__ W_fc,
                                            const float* __restrict__ b_fc,
                                            float* __restrict__ out) {
    __shared__ float pl[2][NH];
    const int b0 = blockIdx.x * 2;
    for (int i = threadIdx.x; i < 2 * NH; i += 256)
        pl[i >> 9][i & 511] = pooled[(size_t)b0 * NH + i];
    __syncthreads();
    const int o = threadIdx.x & 127, bl = threadIdx.x >> 7;
    const float* wr = W_fc + (size_t)o * NH;
    float acc = 0.f;
    #pragma unroll 4
    for (int k = 0; k < NH; k += 4) {
        const float4 wv = *(const float4*)&wr[k];
        acc += pl[bl][k] * wv.x + pl[bl][k + 1] * wv.y +
               pl[bl][k + 2] * wv.z + pl[bl][k + 3] * wv.w;
    }
    out[(size_t)(b0 + bl) * NO + o] = acc + b_fc[o];
}

extern "C" void kernel_launch(void* const* d_in, const int* in_sizes, int n_in,
                              void* d_out, int out_size, void* d_ws, size_t ws_size,
                              hipStream_t stream) {
    const float* x     = (const float*)d_in[0];
    const float* W_emb = (const float*)d_in[1];
    const float* b_emb = (const float*)d_in[2];
    const float* W_ih  = (const float*)d_in[3];
    const float* W_hh  = (const float*)d_in[4];
    const float* b_ih  = (const float*)d_in[5];
    const float* b_hh  = (const float*)d_in[6];
    const float* W_fc  = (const float*)d_in[7];
    const float* b_fc  = (const float*)d_in[8];
    float* out = (float*)d_out;
    float* ws  = (float*)d_ws;

    float* W_comb = ws + OFF_WCOMB;
    float* b_comb = ws + OFF_BCOMB;
    u32*   hbuf   = (u32*)(ws + OFF_HBUF);
    float* pooled = ws + OFF_POOL;

    hipLaunchKernelGGL(k_wcomb, dim3(512), dim3(256), 0, stream,
                       W_emb, b_emb, W_ih, b_ih, b_hh, W_comb, b_comb);
    hipLaunchKernelGGL(k_lstm,  dim3(128), dim3(512), 0, stream,
                       x, W_hh, W_comb, b_comb, hbuf, pooled);
    hipLaunchKernelGGL(k_fc,    dim3(32),  dim3(256), 0, stream,
                       pooled, W_fc, b_fc, out);
}